// Round 5
// baseline (397.451 us; speedup 1.0000x reference)
//
#include <hip/hip_runtime.h>
#include <math.h>

#define NH 32
#define NKVH 8
#define GRP 4
#define HD 128
#define LQB 128
#define B_SEQ 8
#define PTSTRIDE 128
#define KVROW (NKVH * HD)          // 1024 floats per token row
#define QK_SCALE 0.08838834764831845f
#define LOG2E 1.4426950408889634f
#define DEFER_THR 8.0f
#define NROWS (B_SEQ * LQB * NH)   // 32768 (q-row, head) pairs

typedef __attribute__((ext_vector_type(8))) __bf16 bf16x8;
typedef __attribute__((ext_vector_type(4))) __bf16 bf16x4;
typedef __attribute__((ext_vector_type(4))) float f32x4;

// LDS per buffer: K: 32 keys x 128 d bf16, 256B rows, 16-slot XOR swizzle ((row&15)<<4)
//                 Vt: 128 d x 40 keys bf16 (80B rows, reads 2-way free)
#define KS_BYTES 8192
#define VT_STRIDE 80
#define VT_BYTES 10240
#define KS_OFF(b) ((b) * KS_BYTES)
#define VT_OFF(b) (2 * KS_BYTES + (b) * VT_BYTES)
// total LDS = 36864 B; 3 blocks/CU (VGPR-capped) = 110 KB of 160 KB

static __device__ __forceinline__ bf16x8 cvt8s(const float* __restrict__ p, float s) {
    const f32x4 a = *reinterpret_cast<const f32x4*>(p);
    const f32x4 b = *reinterpret_cast<const f32x4*>(p + 4);
    bf16x8 r;
    r[0] = (__bf16)(a[0] * s); r[1] = (__bf16)(a[1] * s);
    r[2] = (__bf16)(a[2] * s); r[3] = (__bf16)(a[3] * s);
    r[4] = (__bf16)(b[0] * s); r[5] = (__bf16)(b[1] * s);
    r[6] = (__bf16)(b[2] * s); r[7] = (__bf16)(b[3] * s);
    return r;
}

// Wave = 32 q-rows (2 x 16-row fragments) of one head; block = 4 heads of one kv
// group sharing K/V in LDS. Every K ds_read_b128 / V ds_read_b64 feeds TWO MFMAs.
// Swapped QK^T => softmax lane-local per fragment; deferred-max rescale.
// NSPLIT-way flash-decoding split over keys; partials combined by a second kernel.
template<int NSPLIT>
__global__ __launch_bounds__(256, 3)
void attn_fwd(const float* __restrict__ Q,
              const float* __restrict__ Kn,
              const float* __restrict__ Vn,
              const float* __restrict__ Kc,
              const float* __restrict__ Vc,
              const int* __restrict__ PT,
              const int* __restrict__ CTX,
              float* __restrict__ O,
              float* __restrict__ WA,      // [NSPLIT][NROWS][HD] unnormalized partial O
              float2* __restrict__ WML)    // [NSPLIT][NROWS] (m, l), log2 domain
{
    __shared__ __align__(16) unsigned char smem[2 * KS_BYTES + 2 * VT_BYTES];

    const int ctx  = CTX[0];                 // 2048 (multiple of 32)
    const int tid  = (int)threadIdx.x;
    const int wave = tid >> 6;
    const int lane = tid & 63;
    const int low  = lane & 15;
    const int hi   = lane >> 4;

    // XCD mapping: all blocks of one (b,kvh) share bid%8 -> same XCD L2
    const int bid   = (int)blockIdx.x;
    const int kvh   = bid & 7;
    const int b     = (bid >> 3) & 7;
    const int qtile = (bid >> 6) & 3;        // 32-row q tiles (uniform visibility!)
    const int sk    = bid >> 8;              // split index
    const int head  = kvh * GRP + wave;
    const int q0    = qtile * 32;

    const int qtok = b * LQB + q0 + low;     // fragment 0 row; fragment 1 = +16
    const float* qrow0 = Q + (size_t)qtok * (NH * HD) + head * HD;
    const float* qrow1 = qrow0 + 16 * (NH * HD);

    bf16x8 qf0[4], qf1[4];                   // Q B-fragments, scale*log2e folded
    #pragma unroll
    for (int c = 0; c < 4; ++c) {
        qf0[c] = cvt8s(qrow0 + 32 * c + 8 * hi, QK_SCALE * LOG2E);
        qf1[c] = cvt8s(qrow1 + 32 * c + 8 * hi, QK_SCALE * LOG2E);
    }

    f32x4 acc0[8], acc1[8];
    #pragma unroll
    for (int c = 0; c < 8; ++c) {
        acc0[c] = (f32x4){0.f, 0.f, 0.f, 0.f};
        acc1[c] = (f32x4){0.f, 0.f, 0.f, 0.f};
    }
    float m0 = -1e30f, l0 = 0.f, m1 = -1e30f, l1 = 0.f;

    const int vis  = ctx + q0 + 32;          // visible keys (multiple of 32)
    const int nt   = vis >> 5;               // 32-key tiles
    const int kbeg = ((nt * sk) / NSPLIT) << 5;
    const int kend = ((nt * (sk + 1)) / NSPLIT) << 5;
    const int nsteps = (kend - kbeg) >> 5;

    // staging ids
    const int skey = tid >> 3;               // K: key row 0..31
    const int sc8  = tid & 7;                // K: 16-float col chunk
    const int kxr  = (skey & 15) << 4;       // 16-slot swizzle
    const int vdc  = tid >> 3;               // V: d-chunk (4 floats) 0..31
    const int vkq  = tid & 7;                // V: key quad 0..7

    f32x4 kr[4], vr[4];                      // in-flight staging registers

    auto issue_loads = [&](int t0) {
        {   // K row skey, 16 floats at 16*sc8
            const int tok = t0 + skey;
            const float* src; size_t ro;
            if (tok < ctx) {
                const int pg = PT[b * PTSTRIDE + (tok >> 4)];
                src = Kc; ro = ((size_t)pg * 16 + (tok & 15)) * KVROW + kvh * HD;
            } else {
                src = Kn; ro = (size_t)(b * LQB + tok - ctx) * KVROW + kvh * HD;
            }
            const f32x4* p = reinterpret_cast<const f32x4*>(src + ro + 16 * sc8);
            kr[0] = p[0]; kr[1] = p[1]; kr[2] = p[2]; kr[3] = p[3];
        }
        {   // V: 4 consecutive key rows (4-aligned -> same page), 4 d each
            const int tok0 = t0 + 4 * vkq;
            const float* src; size_t ro;
            if (tok0 < ctx) {
                const int pg = PT[b * PTSTRIDE + (tok0 >> 4)];
                src = Vc; ro = ((size_t)pg * 16 + (tok0 & 15)) * KVROW + kvh * HD;
            } else {
                src = Vn; ro = (size_t)(b * LQB + tok0 - ctx) * KVROW + kvh * HD;
            }
            const float* base = src + ro + 4 * vdc;
            vr[0] = *reinterpret_cast<const f32x4*>(base);
            vr[1] = *reinterpret_cast<const f32x4*>(base + KVROW);
            vr[2] = *reinterpret_cast<const f32x4*>(base + 2 * KVROW);
            vr[3] = *reinterpret_cast<const f32x4*>(base + 3 * KVROW);
        }
    };

    auto write_k = [&](int buf) {
        unsigned char* ks = smem + KS_OFF(buf) + skey * 256;
        bf16x8 c0w, c1w;
        #pragma unroll
        for (int j = 0; j < 4; ++j) {
            c0w[j] = (__bf16)kr[0][j]; c0w[j + 4] = (__bf16)kr[1][j];
            c1w[j] = (__bf16)kr[2][j]; c1w[j + 4] = (__bf16)kr[3][j];
        }
        *reinterpret_cast<bf16x8*>(ks + ((32 * sc8) ^ kxr))      = c0w;
        *reinterpret_cast<bf16x8*>(ks + ((32 * sc8 + 16) ^ kxr)) = c1w;
    };
    auto write_v = [&](int buf) {
        unsigned char* vt = smem + VT_OFF(buf) + 8 * vkq;
        #pragma unroll
        for (int di = 0; di < 4; ++di) {
            bf16x4 w;
            w[0] = (__bf16)vr[0][di]; w[1] = (__bf16)vr[1][di];
            w[2] = (__bf16)vr[2][di]; w[3] = (__bf16)vr[3][di];
            *reinterpret_cast<bf16x4*>(vt + (4 * vdc + di) * VT_STRIDE) = w;
        }
    };

    issue_loads(kbeg);
    write_k(0); write_v(0);
    __syncthreads();

    int cur = 0;
    for (int s = 0; s < nsteps; ++s) {
        if (s + 1 < nsteps) issue_loads(kbeg + ((s + 1) << 5));

        const unsigned char* ks = smem + KS_OFF(cur);
        const unsigned char* vt = smem + VT_OFF(cur);
        const int xr = low << 4;

        f32x4 s00 = (f32x4){0.f,0.f,0.f,0.f}, s01 = (f32x4){0.f,0.f,0.f,0.f};
        f32x4 s10 = (f32x4){0.f,0.f,0.f,0.f}, s11 = (f32x4){0.f,0.f,0.f,0.f};
        __builtin_amdgcn_s_setprio(1);
        #pragma unroll
        for (int c = 0; c < 4; ++c) {
            bf16x8 ka = *reinterpret_cast<const bf16x8*>(ks + low * 256 + ((64 * c + 16 * hi) ^ xr));
            bf16x8 kb = *reinterpret_cast<const bf16x8*>(ks + (16 + low) * 256 + ((64 * c + 16 * hi) ^ xr));
            s00 = __builtin_amdgcn_mfma_f32_16x16x32_bf16(ka, qf0[c], s00, 0, 0, 0);
            s01 = __builtin_amdgcn_mfma_f32_16x16x32_bf16(kb, qf0[c], s01, 0, 0, 0);
            s10 = __builtin_amdgcn_mfma_f32_16x16x32_bf16(ka, qf1[c], s10, 0, 0, 0);
            s11 = __builtin_amdgcn_mfma_f32_16x16x32_bf16(kb, qf1[c], s11, 0, 0, 0);
        }
        __builtin_amdgcn_s_setprio(0);

        if (s + 1 < nsteps) write_k(cur ^ 1);   // kr dies here (shorter liveness)

        float pm0 = fmaxf(fmaxf(fmaxf(s00[0], s00[1]), fmaxf(s00[2], s00[3])),
                          fmaxf(fmaxf(s01[0], s01[1]), fmaxf(s01[2], s01[3])));
        float pm1 = fmaxf(fmaxf(fmaxf(s10[0], s10[1]), fmaxf(s10[2], s10[3])),
                          fmaxf(fmaxf(s11[0], s11[1]), fmaxf(s11[2], s11[3])));

        // deferred-max: cross-lane reduce + rescale only when a bound grows
        if (!__all((pm0 - m0 <= DEFER_THR) && (pm1 - m1 <= DEFER_THR))) {
            float r0 = fmaxf(pm0, __shfl_xor(pm0, 16));
            r0 = fmaxf(r0, __shfl_xor(r0, 32));
            float r1 = fmaxf(pm1, __shfl_xor(pm1, 16));
            r1 = fmaxf(r1, __shfl_xor(r1, 32));
            const float n0 = fmaxf(m0, r0), n1 = fmaxf(m1, r1);
            const float c0f = exp2f(m0 - n0), c1f = exp2f(m1 - n1);
            m0 = n0; m1 = n1;
            l0 *= c0f; l1 *= c1f;
            #pragma unroll
            for (int c = 0; c < 8; ++c) { acc0[c] *= c0f; acc1[c] *= c1f; }
        }

        float p0[8], p1[8];
        #pragma unroll
        for (int j = 0; j < 4; ++j) {
            p0[j]     = exp2f(s00[j] - m0);
            p0[j + 4] = exp2f(s01[j] - m0);
            p1[j]     = exp2f(s10[j] - m1);
            p1[j + 4] = exp2f(s11[j] - m1);
        }
        l0 += ((p0[0] + p0[1]) + (p0[2] + p0[3])) + ((p0[4] + p0[5]) + (p0[6] + p0[7]));
        l1 += ((p1[0] + p1[1]) + (p1[2] + p1[3])) + ((p1[4] + p1[5]) + (p1[6] + p1[7]));

        bf16x8 pf0, pf1;
        #pragma unroll
        for (int j = 0; j < 8; ++j) { pf0[j] = (__bf16)p0[j]; pf1[j] = (__bf16)p1[j]; }

        __builtin_amdgcn_s_setprio(1);
        #pragma unroll
        for (int c = 0; c < 8; ++c) {
            const unsigned char* vrow = vt + (16 * c + low) * VT_STRIDE + 8 * hi;
            bf16x4 a0 = *reinterpret_cast<const bf16x4*>(vrow);
            bf16x4 a1 = *reinterpret_cast<const bf16x4*>(vrow + 32);
            bf16x8 vf;
            vf[0] = a0[0]; vf[1] = a0[1]; vf[2] = a0[2]; vf[3] = a0[3];
            vf[4] = a1[0]; vf[5] = a1[1]; vf[6] = a1[2]; vf[7] = a1[3];
            acc0[c] = __builtin_amdgcn_mfma_f32_16x16x32_bf16(vf, pf0, acc0[c], 0, 0, 0);
            acc1[c] = __builtin_amdgcn_mfma_f32_16x16x32_bf16(vf, pf1, acc1[c], 0, 0, 0);
        }
        __builtin_amdgcn_s_setprio(0);

        if (s + 1 < nsteps) write_v(cur ^ 1);
        __syncthreads();
        cur ^= 1;
    }

    l0 += __shfl_xor(l0, 16); l0 += __shfl_xor(l0, 32);
    l1 += __shfl_xor(l1, 16); l1 += __shfl_xor(l1, 32);

    const int r0 = qtok * NH + head;
    const int r1 = r0 + 16 * NH;
    if (NSPLIT > 1) {
        float* oa0 = WA + ((size_t)sk * NROWS + r0) * HD;
        float* oa1 = WA + ((size_t)sk * NROWS + r1) * HD;
        #pragma unroll
        for (int c = 0; c < 8; ++c) {
            *reinterpret_cast<f32x4*>(oa0 + 16 * c + 4 * hi) = acc0[c];
            *reinterpret_cast<f32x4*>(oa1 + 16 * c + 4 * hi) = acc1[c];
        }
        if (hi == 0) {
            WML[sk * NROWS + r0] = make_float2(m0, l0);
            WML[sk * NROWS + r1] = make_float2(m1, l1);
        }
    } else {
        const float i0 = 1.0f / l0, i1 = 1.0f / l1;
        float* o0 = O + (size_t)r0 * HD;
        float* o1 = O + (size_t)r1 * HD;
        #pragma unroll
        for (int c = 0; c < 8; ++c) {
            f32x4 v0 = acc0[c] * i0, v1 = acc1[c] * i1;
            *reinterpret_cast<f32x4*>(o0 + 16 * c + 4 * hi) = v0;
            *reinterpret_cast<f32x4*>(o1 + 16 * c + 4 * hi) = v1;
        }
    }
}

template<int NSPLIT>
__global__ __launch_bounds__(256)
void combine(const float* __restrict__ WA, const float2* __restrict__ WML,
             float* __restrict__ O)
{
    const int idx = (int)blockIdx.x * 256 + (int)threadIdx.x;  // NROWS*32 threads
    const int r  = idx >> 5;
    const int dq = idx & 31;
    float2 ml[NSPLIT];
    float M = -1e30f;
    #pragma unroll
    for (int s = 0; s < NSPLIT; ++s) { ml[s] = WML[s * NROWS + r]; M = fmaxf(M, ml[s].x); }
    float e[NSPLIT];
    float den = 0.f;
    #pragma unroll
    for (int s = 0; s < NSPLIT; ++s) { e[s] = exp2f(ml[s].x - M); den += ml[s].y * e[s]; }
    const float inv = 1.0f / den;
    f32x4 o = (f32x4){0.f, 0.f, 0.f, 0.f};
    #pragma unroll
    for (int s = 0; s < NSPLIT; ++s) {
        const f32x4 a = *reinterpret_cast<const f32x4*>(WA + ((size_t)s * NROWS + r) * HD + 4 * dq);
        o += a * e[s];
    }
    o *= inv;
    *reinterpret_cast<f32x4*>(O + (size_t)r * HD + 4 * dq) = o;
}

extern "C" void kernel_launch(void* const* d_in, const int* in_sizes, int n_in,
                              void* d_out, int out_size, void* d_ws, size_t ws_size,
                              hipStream_t stream) {
    const float* q  = (const float*)d_in[0];
    const float* k  = (const float*)d_in[1];
    const float* v  = (const float*)d_in[2];
    const float* kc = (const float*)d_in[3];
    const float* vc = (const float*)d_in[4];
    const int*   pt = (const int*)d_in[5];
    const int*   cx = (const int*)d_in[6];
    float* out = (float*)d_out;

    const size_t wa4 = (size_t)4 * NROWS * HD * sizeof(float);
    const size_t need4 = wa4 + (size_t)4 * NROWS * sizeof(float2);
    const size_t wa2 = (size_t)2 * NROWS * HD * sizeof(float);
    const size_t need2 = wa2 + (size_t)2 * NROWS * sizeof(float2);

    if (ws_size >= need4) {
        float*  wa  = (float*)d_ws;
        float2* wml = (float2*)((char*)d_ws + wa4);
        attn_fwd<4><<<dim3(1024), dim3(256), 0, stream>>>(q, k, v, kc, vc, pt, cx, out, wa, wml);
        combine<4><<<dim3(NROWS * 32 / 256), dim3(256), 0, stream>>>(wa, wml, out);
    } else if (ws_size >= need2) {
        float*  wa  = (float*)d_ws;
        float2* wml = (float2*)((char*)d_ws + wa2);
        attn_fwd<2><<<dim3(512), dim3(256), 0, stream>>>(q, k, v, kc, vc, pt, cx, out, wa, wml);
        combine<2><<<dim3(NROWS * 32 / 256), dim3(256), 0, stream>>>(wa, wml, out);
    } else {
        attn_fwd<1><<<dim3(256), dim3(256), 0, stream>>>(q, k, v, kc, vc, pt, cx, out,
                                                         nullptr, nullptr);
    }
}

// Round 6
// 270.736 us; speedup vs baseline: 1.4680x; 1.4680x over previous
//
#include <hip/hip_runtime.h>
#include <math.h>

#define NH 32
#define NKVH 8
#define GRP 4
#define HD 128
#define LQB 128
#define B_SEQ 8
#define PTSTRIDE 128
#define KVROW (NKVH * HD)          // 1024 floats per token row
#define QK_SCALE 0.08838834764831845f
#define LOG2E 1.4426950408889634f
#define DEFER_THR 8.0f
#define NROWS (B_SEQ * LQB * NH)   // 32768 (q-row, head) pairs

typedef __attribute__((ext_vector_type(8))) __bf16 bf16x8;
typedef __attribute__((ext_vector_type(4))) __bf16 bf16x4;
typedef __attribute__((ext_vector_type(4))) float f32x4;

// LDS per buffer: K: 32 keys x 128 d bf16, 256B rows, 16-slot XOR swizzle ((row&15)<<4)
//                 Vt: 128 d x 40 keys bf16 (80B rows, reads 2-way free)
#define KS_BYTES 8192
#define VT_STRIDE 80
#define VT_BYTES 10240
#define KS_OFF(b) ((b) * KS_BYTES)
#define VT_OFF(b) (2 * KS_BYTES + (b) * VT_BYTES)
// total LDS = 36864 B -> 4 blocks/CU (144 KB of 160 KB)

static __device__ __forceinline__ bf16x8 cvt8s(const float* __restrict__ p, float s) {
    const f32x4 a = *reinterpret_cast<const f32x4*>(p);
    const f32x4 b = *reinterpret_cast<const f32x4*>(p + 4);
    bf16x8 r;
    r[0] = (__bf16)(a[0] * s); r[1] = (__bf16)(a[1] * s);
    r[2] = (__bf16)(a[2] * s); r[3] = (__bf16)(a[3] * s);
    r[4] = (__bf16)(b[0] * s); r[5] = (__bf16)(b[1] * s);
    r[6] = (__bf16)(b[2] * s); r[7] = (__bf16)(b[3] * s);
    return r;
}

// Wave = 16 q-rows of one head; block = 4 heads of one kv group (shared K/V in LDS).
// Swapped QK^T => softmax lane-local (2 shfl only on deferred-max rescale steps).
// NSPLIT-way flash-decoding split over keys; partials combined by a second kernel.
// Staging pipeline is 2-deep: write_tile(s+1) at step top (loads issued a full step
// earlier), then issue loads for s+2; raw s_barrier drains ONLY lgkmcnt so the
// global loads stay in flight across the barrier (T4/T14).
template<int NSPLIT>
__global__ __launch_bounds__(256, 4)
void attn_fwd(const float* __restrict__ Q,
              const float* __restrict__ Kn,
              const float* __restrict__ Vn,
              const float* __restrict__ Kc,
              const float* __restrict__ Vc,
              const int* __restrict__ PT,
              const int* __restrict__ CTX,
              float* __restrict__ O,
              float* __restrict__ WA,      // [NSPLIT][NROWS][HD] unnormalized partial O
              float2* __restrict__ WML)    // [NSPLIT][NROWS] (m, l), log2 domain
{
    __shared__ __align__(16) unsigned char smem[2 * KS_BYTES + 2 * VT_BYTES];

    const int ctx  = CTX[0];                 // 2048 (multiple of 32)
    const int tid  = (int)threadIdx.x;
    const int wave = tid >> 6;
    const int lane = tid & 63;
    const int low  = lane & 15;
    const int hi   = lane >> 4;

    // XCD mapping: all blocks of one (b,kvh) share bid%8 -> same XCD L2
    const int bid   = (int)blockIdx.x;
    const int kvh   = bid & 7;
    const int b     = (bid >> 3) & 7;
    const int qtile = (bid >> 6) & 7;
    const int sk    = (NSPLIT > 1) ? (bid >> 9) : 0;
    const int head  = kvh * GRP + wave;
    const int q0    = qtile * 16;

    const int qtok = b * LQB + q0 + low;
    const float* qrow = Q + (size_t)qtok * (NH * HD) + head * HD;

    bf16x8 qf[4];                            // Q B-fragments, scale*log2e folded
    #pragma unroll
    for (int c = 0; c < 4; ++c) qf[c] = cvt8s(qrow + 32 * c + 8 * hi, QK_SCALE * LOG2E);

    f32x4 acc[8];
    #pragma unroll
    for (int c = 0; c < 8; ++c) acc[c] = (f32x4){0.f, 0.f, 0.f, 0.f};
    float mrun = -1e30f, lrun = 0.f;

    const int vis  = ctx + (((q0 >> 5) + 1) << 5);   // visible keys (mult of 32)
    const int nt   = vis >> 5;                        // 32-key tiles
    const int kbeg = ((nt * sk) / NSPLIT) << 5;
    const int kend = ((nt * (sk + 1)) / NSPLIT) << 5;
    const int nsteps = (kend - kbeg) >> 5;

    // staging ids
    const int skey = tid >> 3;               // K: key row 0..31
    const int sc8  = tid & 7;                // K: 16-float col chunk
    const int kxr  = (skey & 15) << 4;       // 16-slot swizzle
    const int vdc  = tid >> 3;               // V: d-chunk (4 floats) 0..31
    const int vkq  = tid & 7;                // V: key quad 0..7

    f32x4 kr[4], vr[4];                      // in-flight staging registers

    auto issue_loads = [&](int t0) {
        {   // K row skey, 16 floats at 16*sc8
            const int tok = t0 + skey;
            const float* src; size_t ro;
            if (tok < ctx) {
                const int pg = PT[b * PTSTRIDE + (tok >> 4)];
                src = Kc; ro = ((size_t)pg * 16 + (tok & 15)) * KVROW + kvh * HD;
            } else {
                src = Kn; ro = (size_t)(b * LQB + tok - ctx) * KVROW + kvh * HD;
            }
            const f32x4* p = reinterpret_cast<const f32x4*>(src + ro + 16 * sc8);
            kr[0] = p[0]; kr[1] = p[1]; kr[2] = p[2]; kr[3] = p[3];
        }
        {   // V: 4 consecutive key rows (4-aligned -> same page), 4 d each
            const int tok0 = t0 + 4 * vkq;
            const float* src; size_t ro;
            if (tok0 < ctx) {
                const int pg = PT[b * PTSTRIDE + (tok0 >> 4)];
                src = Vc; ro = ((size_t)pg * 16 + (tok0 & 15)) * KVROW + kvh * HD;
            } else {
                src = Vn; ro = (size_t)(b * LQB + tok0 - ctx) * KVROW + kvh * HD;
            }
            const float* base = src + ro + 4 * vdc;
            vr[0] = *reinterpret_cast<const f32x4*>(base);
            vr[1] = *reinterpret_cast<const f32x4*>(base + KVROW);
            vr[2] = *reinterpret_cast<const f32x4*>(base + 2 * KVROW);
            vr[3] = *reinterpret_cast<const f32x4*>(base + 3 * KVROW);
        }
    };

    auto write_tile = [&](int buf) {
        unsigned char* ks = smem + KS_OFF(buf) + skey * 256;
        bf16x8 c0w, c1w;
        #pragma unroll
        for (int j = 0; j < 4; ++j) {
            c0w[j] = (__bf16)kr[0][j]; c0w[j + 4] = (__bf16)kr[1][j];
            c1w[j] = (__bf16)kr[2][j]; c1w[j + 4] = (__bf16)kr[3][j];
        }
        *reinterpret_cast<bf16x8*>(ks + ((32 * sc8) ^ kxr))      = c0w;
        *reinterpret_cast<bf16x8*>(ks + ((32 * sc8 + 16) ^ kxr)) = c1w;
        unsigned char* vt = smem + VT_OFF(buf) + 8 * vkq;
        #pragma unroll
        for (int di = 0; di < 4; ++di) {
            bf16x4 w;
            w[0] = (__bf16)vr[0][di]; w[1] = (__bf16)vr[1][di];
            w[2] = (__bf16)vr[2][di]; w[3] = (__bf16)vr[3][di];
            *reinterpret_cast<bf16x4*>(vt + (4 * vdc + di) * VT_STRIDE) = w;
        }
    };

    // LDS-only drain + raw barrier: global staging loads stay in flight across it
    auto tile_barrier = [&]() {
        asm volatile("s_waitcnt lgkmcnt(0)" ::: "memory");
        __builtin_amdgcn_s_barrier();
    };

    // prologue: tile0 -> LDS buf0; tile1 -> regs (in flight across the barrier)
    issue_loads(kbeg);
    write_tile(0);
    if (nsteps > 1) issue_loads(kbeg + 32);
    tile_barrier();

    int cur = 0;
    for (int s = 0; s < nsteps; ++s) {
        if (s + 1 < nsteps) write_tile(cur ^ 1);            // regs are a full step old
        if (s + 2 < nsteps) issue_loads(kbeg + ((s + 2) << 5));  // 2-deep prefetch

        const unsigned char* ks = smem + KS_OFF(cur);
        const unsigned char* vt = smem + VT_OFF(cur);
        const int xr = low << 4;

        f32x4 s0 = (f32x4){0.f, 0.f, 0.f, 0.f};
        f32x4 s1 = (f32x4){0.f, 0.f, 0.f, 0.f};
        #pragma unroll
        for (int c = 0; c < 4; ++c) {
            bf16x8 ka = *reinterpret_cast<const bf16x8*>(ks + low * 256 + ((64 * c + 16 * hi) ^ xr));
            bf16x8 kb = *reinterpret_cast<const bf16x8*>(ks + (16 + low) * 256 + ((64 * c + 16 * hi) ^ xr));
            s0 = __builtin_amdgcn_mfma_f32_16x16x32_bf16(ka, qf[c], s0, 0, 0, 0);
            s1 = __builtin_amdgcn_mfma_f32_16x16x32_bf16(kb, qf[c], s1, 0, 0, 0);
        }

        float pmax = fmaxf(fmaxf(fmaxf(s0[0], s0[1]), fmaxf(s0[2], s0[3])),
                           fmaxf(fmaxf(s1[0], s1[1]), fmaxf(s1[2], s1[3])));

        // deferred-max: cross-lane reduce + rescale only when the bound grows
        if (!__all(pmax - mrun <= DEFER_THR)) {
            float pm = fmaxf(pmax, __shfl_xor(pmax, 16));
            pm = fmaxf(pm, __shfl_xor(pm, 32));
            const float mnew = fmaxf(mrun, pm);
            const float corr = exp2f(mrun - mnew);
            mrun = mnew;
            lrun *= corr;
            #pragma unroll
            for (int c = 0; c < 8; ++c) acc[c] *= corr;
        }

        float p[8];
        #pragma unroll
        for (int j = 0; j < 4; ++j) {
            p[j]     = exp2f(s0[j] - mrun);
            p[j + 4] = exp2f(s1[j] - mrun);
        }
        lrun += (((p[0] + p[1]) + (p[2] + p[3])) + ((p[4] + p[5]) + (p[6] + p[7])));

        bf16x8 pf;
        #pragma unroll
        for (int j = 0; j < 8; ++j) pf[j] = (__bf16)p[j];

        #pragma unroll
        for (int c = 0; c < 8; ++c) {
            const unsigned char* vrow = vt + (16 * c + low) * VT_STRIDE + 8 * hi;
            bf16x4 a0 = *reinterpret_cast<const bf16x4*>(vrow);
            bf16x4 a1 = *reinterpret_cast<const bf16x4*>(vrow + 32);
            bf16x8 vf;
            vf[0] = a0[0]; vf[1] = a0[1]; vf[2] = a0[2]; vf[3] = a0[3];
            vf[4] = a1[0]; vf[5] = a1[1]; vf[6] = a1[2]; vf[7] = a1[3];
            acc[c] = __builtin_amdgcn_mfma_f32_16x16x32_bf16(vf, pf, acc[c], 0, 0, 0);
        }

        if (s + 1 < nsteps) tile_barrier();   // last step needs no barrier
        cur ^= 1;
    }

    lrun += __shfl_xor(lrun, 16);
    lrun += __shfl_xor(lrun, 32);

    const int r = qtok * NH + head;          // (q-row, head) index, 0..NROWS
    if (NSPLIT > 1) {
        float* oa = WA + ((size_t)sk * NROWS + r) * HD;
        #pragma unroll
        for (int c = 0; c < 8; ++c)
            *reinterpret_cast<f32x4*>(oa + 16 * c + 4 * hi) = acc[c];
        if (hi == 0) WML[sk * NROWS + r] = make_float2(mrun, lrun);
    } else {
        const float inv = 1.0f / lrun;
        float* orow = O + (size_t)r * HD;
        #pragma unroll
        for (int c = 0; c < 8; ++c) {
            f32x4 v = acc[c] * inv;
            *reinterpret_cast<f32x4*>(orow + 16 * c + 4 * hi) = v;
        }
    }
}

template<int NSPLIT>
__global__ __launch_bounds__(256)
void combine(const float* __restrict__ WA, const float2* __restrict__ WML,
             float* __restrict__ O)
{
    const int idx = (int)blockIdx.x * 256 + (int)threadIdx.x;  // NROWS*32 threads
    const int r  = idx >> 5;
    const int dq = idx & 31;
    float2 ml[NSPLIT];
    float M = -1e30f;
    #pragma unroll
    for (int s = 0; s < NSPLIT; ++s) { ml[s] = WML[s * NROWS + r]; M = fmaxf(M, ml[s].x); }
    float e[NSPLIT];
    float den = 0.f;
    #pragma unroll
    for (int s = 0; s < NSPLIT; ++s) { e[s] = exp2f(ml[s].x - M); den += ml[s].y * e[s]; }
    const float inv = 1.0f / den;
    f32x4 o = (f32x4){0.f, 0.f, 0.f, 0.f};
    #pragma unroll
    for (int s = 0; s < NSPLIT; ++s) {
        const f32x4 a = *reinterpret_cast<const f32x4*>(WA + ((size_t)s * NROWS + r) * HD + 4 * dq);
        o += a * e[s];
    }
    o *= inv;
    *reinterpret_cast<f32x4*>(O + (size_t)r * HD + 4 * dq) = o;
}

extern "C" void kernel_launch(void* const* d_in, const int* in_sizes, int n_in,
                              void* d_out, int out_size, void* d_ws, size_t ws_size,
                              hipStream_t stream) {
    const float* q  = (const float*)d_in[0];
    const float* k  = (const float*)d_in[1];
    const float* v  = (const float*)d_in[2];
    const float* kc = (const float*)d_in[3];
    const float* vc = (const float*)d_in[4];
    const int*   pt = (const int*)d_in[5];
    const int*   cx = (const int*)d_in[6];
    float* out = (float*)d_out;

    const size_t wa2   = (size_t)2 * NROWS * HD * sizeof(float);
    const size_t need2 = wa2 + (size_t)2 * NROWS * sizeof(float2);

    if (ws_size >= need2) {
        float*  wa  = (float*)d_ws;
        float2* wml = (float2*)((char*)d_ws + wa2);
        attn_fwd<2><<<dim3(1024), dim3(256), 0, stream>>>(q, k, v, kc, vc, pt, cx, out, wa, wml);
        combine<2><<<dim3(NROWS * 32 / 256), dim3(256), 0, stream>>>(wa, wml, out);
    } else {
        attn_fwd<1><<<dim3(512), dim3(256), 0, stream>>>(q, k, v, kc, vc, pt, cx, out,
                                                         nullptr, nullptr);
    }
}